// Round 11
// baseline (8705.104 us; speedup 1.0000x reference)
//
#include <hip/hip_runtime.h>
#include <stdint.h>
#include <math.h>

// ---------------------------------------------------------------------------
// QuantumDiffusionDreamer — round 11: r10 (measured best 8.39 ms) with the
// four pipeline GEMMs retiled 128x128/8x(32x64) -> 256x128/8x(64x64).
// Theory: measured 22% MFMA eff ≈ LDS-BW bound (96KB reads + 32KB writes vs
// 155 cyc MFMA per CU-iter). 64x64 per-wave tiles halve LDS bytes/FLOP ->
// bound rises to ~35-40%. Same K-accumulation order -> bit-identical output.
// G7 stays r10's fused 64x128 update kernel (measured good).
// r8 lesson: bank-balanced 16x16 frag reads. r7 lesson: PRNG only at high
// occupancy. PRNG: JAX threefry2x32 partitionable. x stays fp32.
// ---------------------------------------------------------------------------

typedef __bf16 bf16x8 __attribute__((ext_vector_type(8)));
typedef float floatx4 __attribute__((ext_vector_type(4)));

__host__ __device__ inline void tf2x32(uint32_t k0, uint32_t k1,
                                       uint32_t x0, uint32_t x1,
                                       uint32_t& o0, uint32_t& o1) {
  uint32_t ks2 = k0 ^ k1 ^ 0x1BD11BDAu;
#define TF_R(r) { x0 += x1; x1 = (x1 << (r)) | (x1 >> (32 - (r))); x1 ^= x0; }
  x0 += k0; x1 += k1;
  TF_R(13) TF_R(15) TF_R(26) TF_R(6)
  x0 += k1;  x1 += ks2 + 1u;
  TF_R(17) TF_R(29) TF_R(16) TF_R(24)
  x0 += ks2; x1 += k0 + 2u;
  TF_R(13) TF_R(15) TF_R(26) TF_R(6)
  x0 += k0;  x1 += k1 + 3u;
  TF_R(17) TF_R(29) TF_R(16) TF_R(24)
  x0 += k1;  x1 += ks2 + 4u;
  TF_R(13) TF_R(15) TF_R(26) TF_R(6)
  x0 += ks2; x1 += k0 + 5u;
#undef TF_R
  o0 = x0; o1 = x1;
}

__device__ inline float erfinv_f32(float x) {
  float w = -log1pf(-x * x);
  float p;
  if (w < 5.0f) {
    w = w - 2.5f;
    p = 2.81022636e-08f;
    p = fmaf(p, w, 3.43273939e-07f);
    p = fmaf(p, w, -3.5233877e-06f);
    p = fmaf(p, w, -4.39150654e-06f);
    p = fmaf(p, w, 0.00021858087f);
    p = fmaf(p, w, -0.00125372503f);
    p = fmaf(p, w, -0.00417768164f);
    p = fmaf(p, w, 0.246640727f);
    p = fmaf(p, w, 1.50140941f);
  } else {
    w = sqrtf(w) - 3.0f;
    p = -0.000200214257f;
    p = fmaf(p, w, 0.000100950558f);
    p = fmaf(p, w, 0.00134934322f);
    p = fmaf(p, w, -0.00367342844f);
    p = fmaf(p, w, 0.00573950773f);
    p = fmaf(p, w, -0.0076224613f);
    p = fmaf(p, w, 0.00943887047f);
    p = fmaf(p, w, 1.00167406f);
    p = fmaf(p, w, 2.83297682f);
  }
  return p * x;
}

__device__ inline float tf_normal(uint32_t k0, uint32_t k1, uint32_t i) {
  uint32_t o0, o1;
  tf2x32(k0, k1, 0u, i, o0, o1);
  uint32_t bits = o0 ^ o1;  // partitionable random_bits path
  float f = __uint_as_float(0x3F800000u | (bits >> 9)) - 1.0f;  // [0,1)
  float u = f * 2.0f + (-0.99999994f);
  u = fmaxf(-0.99999994f, u);
  return 1.41421356f * erfinv_f32(u);
}

__device__ inline unsigned short f2bf(float f) {
  uint32_t u = __float_as_uint(f);
  u += 0x7FFFu + ((u >> 16) & 1u);   // round-to-nearest-even
  return (unsigned short)(u >> 16);
}
__device__ inline float bf2f(unsigned short h) {
  return __uint_as_float(((uint32_t)h) << 16);
}

// ---------------------------------------------------------------------------
// Weight transpose + bf16 convert: Wt[n][k] = bf16(W[k][n]);  W is [K,N] fp32.
// ---------------------------------------------------------------------------
__global__ __launch_bounds__(256)
void transpose_bf16_kernel(const float* __restrict__ W,
                           unsigned short* __restrict__ Wt, int K, int N) {
  __shared__ float tile[32][33];
  int kb = blockIdx.x * 32, nb = blockIdx.y * 32;
  int tx = threadIdx.x & 31, ty = threadIdx.x >> 5;
#pragma unroll
  for (int i = 0; i < 32; i += 8)
    tile[ty + i][tx] = W[(size_t)(kb + ty + i) * N + nb + tx];
  __syncthreads();
#pragma unroll
  for (int i = 0; i < 32; i += 8)
    Wt[(size_t)(nb + ty + i) * K + kb + tx] = f2bf(tile[tx][ty + i]);
}

// ---------------------------------------------------------------------------
// Double-buffered MFMA core, 256x128 tile, 512 threads (8 waves), each wave
// a 64x64 sub-tile (acc 4x4 of 16x16x32). LDS 48 KB dbuf. Per thread per
// K-tile: 3 global_load_lds(16B) (A rows 0..127, A rows 128..255, B).
// `s_waitcnt vmcnt(3); s_barrier` dbuf. Bank-balanced frag reads (64 B row
// stride). Same K-order as r10 -> bit-identical accumulation.
// ---------------------------------------------------------------------------
__device__ __forceinline__ void gemm_core_db(
    const unsigned short* __restrict__ A0, const unsigned short* __restrict__ A1,
    int lda0, int lda1, int K0, int Ktot,
    const unsigned short* __restrict__ Bt,
    int row0, int col0,
    unsigned short (*As)[256 * 32], unsigned short (*Bs)[128 * 32],
    floatx4 (&acc)[4][4]) {
  const int tid = threadIdx.x;            // 0..511
  const int wave = tid >> 6, lane = tid & 63;
  const int wr = wave >> 1, wc = wave & 1;  // 64-row band / 64-col band
  const int srow = tid >> 2;              // 0..127
  const int sgr = (tid & 3) * 8;          // granule offset (shorts)
  const int fm = lane & 15, quad = lane >> 4;

  auto issue = [&](int kt, int buf) {
    const int k0 = kt * 32;
    const unsigned short* Ap; int kOff, lda;
    if (k0 < K0) { Ap = A0; kOff = k0; lda = lda0; }
    else         { Ap = A1; kOff = k0 - K0; lda = lda1; }
    __builtin_amdgcn_global_load_lds(
        (const __attribute__((address_space(1))) uint32_t*)
            (Ap + (size_t)(row0 + srow) * lda + kOff + sgr),
        (__attribute__((address_space(3))) uint32_t*)(&As[buf][srow * 32 + sgr]),
        16, 0, 0);
    __builtin_amdgcn_global_load_lds(
        (const __attribute__((address_space(1))) uint32_t*)
            (Ap + (size_t)(row0 + 128 + srow) * lda + kOff + sgr),
        (__attribute__((address_space(3))) uint32_t*)(&As[buf][(128 + srow) * 32 + sgr]),
        16, 0, 0);
    __builtin_amdgcn_global_load_lds(
        (const __attribute__((address_space(1))) uint32_t*)
            (Bt + (size_t)(col0 + srow) * Ktot + k0 + sgr),
        (__attribute__((address_space(3))) uint32_t*)(&Bs[buf][srow * 32 + sgr]),
        16, 0, 0);
  };

  const int nk = Ktot >> 5;
  issue(0, 0);
  for (int k = 0; k < nk; k++) {
    const int cur = k & 1;
    if (k + 1 < nk) {
      issue(k + 1, cur ^ 1);
      asm volatile("s_waitcnt vmcnt(3)\ns_barrier" ::: "memory");
    } else {
      asm volatile("s_waitcnt vmcnt(0)\ns_barrier" ::: "memory");
    }
    bf16x8 a[4], b[4];
#pragma unroll
    for (int tm = 0; tm < 4; tm++)
      a[tm] = *(const bf16x8*)(&As[cur][(wr * 64 + tm * 16 + fm) * 32 + quad * 8]);
#pragma unroll
    for (int tn = 0; tn < 4; tn++)
      b[tn] = *(const bf16x8*)(&Bs[cur][(wc * 64 + tn * 16 + fm) * 32 + quad * 8]);
#pragma unroll
    for (int tm = 0; tm < 4; tm++)
#pragma unroll
      for (int tn = 0; tn < 4; tn++)
        acc[tm][tn] = __builtin_amdgcn_mfma_f32_16x16x32_bf16(a[tm], b[tn],
                                                              acc[tm][tn], 0, 0, 0);
    asm volatile("s_barrier" ::: "memory");
  }
}

// XCD-aware swizzle for 256-row tiles: 32 row-blocks. by = id%32, bx = id/32:
// col-blocks of one row-block differ by multiples of 32 -> same id%8 -> same
// XCD (performance heuristic only).
__device__ __forceinline__ void swizzled_block(int& row0, int& col0) {
  int id = blockIdx.x + gridDim.x * blockIdx.y;
  row0 = (id & 31) << 8;
  col0 = (id >> 5) << 7;
}

// Generic GEMM. ACT: 0 none, 1 relu, 2 tanh, 3 gelu(exact),
// 4 = split: cols < nsplit -> relu+bias0 -> C0; else tanh+bias1 -> C1.
template<int ACT>
__global__ __launch_bounds__(512, 2)
void mfma_gemm(const unsigned short* __restrict__ A0,
               const unsigned short* __restrict__ A1,
               int lda0, int lda1, int K0, int Ktot,
               const unsigned short* __restrict__ Bt,
               const float* __restrict__ bias0,
               const float* __restrict__ bias1, int nsplit,
               unsigned short* __restrict__ C0,
               unsigned short* __restrict__ C1, int ldc) {
  __shared__ unsigned short As[2][256 * 32];
  __shared__ unsigned short Bs[2][128 * 32];
  int row0, col0;
  swizzled_block(row0, col0);
  floatx4 acc[4][4];
#pragma unroll
  for (int tm = 0; tm < 4; tm++)
#pragma unroll
    for (int tn = 0; tn < 4; tn++) acc[tm][tn] = (floatx4){0.f, 0.f, 0.f, 0.f};
  gemm_core_db(A0, A1, lda0, lda1, K0, Ktot, Bt, row0, col0, As, Bs, acc);

  const int lane = threadIdx.x & 63, wave = threadIdx.x >> 6;
  const int wr = wave >> 1, wc = wave & 1;
  const int fm = lane & 15, quad = lane >> 4;
  const bool side = (ACT == 4) && (col0 >= nsplit);
  const float* bias = side ? bias1 : bias0;
  unsigned short* C = side ? C1 : C0;
  const int cbase = col0 - (side ? nsplit : 0);
#pragma unroll
  for (int tn = 0; tn < 4; tn++) {
    int col = cbase + wc * 64 + tn * 16 + fm;
    float bv = bias[col];
#pragma unroll
    for (int tm = 0; tm < 4; tm++) {
      int rbase = row0 + wr * 64 + tm * 16 + quad * 4;
#pragma unroll
      for (int r = 0; r < 4; r++) {
        float val = acc[tm][tn][r] + bv;
        if (ACT == 1) val = fmaxf(val, 0.0f);
        if (ACT == 2) val = tanhf(val);
        if (ACT == 3) val = 0.5f * val * (1.0f + erff(val * 0.70710678118654752f));
        if (ACT == 4) val = side ? tanhf(val) : fmaxf(val, 0.0f);
        C[(size_t)(rbase + r) * ldc + col] = f2bf(val);
      }
    }
  }
}

// z-batched pair of independent GEMMs (same shapes). No activation.
__global__ __launch_bounds__(512, 2)
void mfma_gemm_pair(const unsigned short* __restrict__ Aa,
                    const unsigned short* __restrict__ Ab,
                    const unsigned short* __restrict__ Bta,
                    const unsigned short* __restrict__ Btb,
                    const float* __restrict__ biasa,
                    const float* __restrict__ biasb,
                    unsigned short* __restrict__ Ca,
                    unsigned short* __restrict__ Cb,
                    int Ktot, int ldc) {
  __shared__ unsigned short As[2][256 * 32];
  __shared__ unsigned short Bs[2][128 * 32];
  const int z = blockIdx.z;
  const unsigned short* A = z ? Ab : Aa;
  const unsigned short* Bt = z ? Btb : Bta;
  const float* bias = z ? biasb : biasa;
  unsigned short* C = z ? Cb : Ca;
  int row0, col0;
  swizzled_block(row0, col0);
  floatx4 acc[4][4];
#pragma unroll
  for (int tm = 0; tm < 4; tm++)
#pragma unroll
    for (int tn = 0; tn < 4; tn++) acc[tm][tn] = (floatx4){0.f, 0.f, 0.f, 0.f};
  gemm_core_db(A, A, Ktot, Ktot, Ktot, Ktot, Bt, row0, col0, As, Bs, acc);

  const int lane = threadIdx.x & 63, wave = threadIdx.x >> 6;
  const int wr = wave >> 1, wc = wave & 1;
  const int fm = lane & 15, quad = lane >> 4;
#pragma unroll
  for (int tn = 0; tn < 4; tn++) {
    int col = col0 + wc * 64 + tn * 16 + fm;
    float bv = bias[col];
#pragma unroll
    for (int tm = 0; tm < 4; tm++) {
      int rbase = row0 + wr * 64 + tm * 16 + quad * 4;
#pragma unroll
      for (int r = 0; r < 4; r++)
        C[(size_t)(rbase + r) * ldc + col] = f2bf(acc[tm][tn][r] + bv);
    }
  }
}

// ---------------------------------------------------------------------------
// G7 fused (r10, unchanged): itf = hi @ Wi2 + bi2, then full DDPM x-update.
// 64x128 tile, grid 512 blocks, 512 threads (8 waves of 32x32).
// ---------------------------------------------------------------------------
__global__ __launch_bounds__(512, 4)
void mfma_gemm_update(const unsigned short* __restrict__ A,   // hi [8192,1024]
                      const unsigned short* __restrict__ Bt,  // Wi2_t [512][1024]
                      const float* __restrict__ bias,         // bi2
                      const unsigned short* __restrict__ d0,
                      const unsigned short* __restrict__ d1,
                      float* __restrict__ x,
                      unsigned short* __restrict__ xbf,
                      const float* __restrict__ a_amp,
                      const float* __restrict__ b_amp,
                      const float* __restrict__ ph,
                      float coh, float c1, float sqa, float sigma,
                      int add_noise, uint32_t k0, uint32_t k1) {
  __shared__ unsigned short As[2][64 * 32];
  __shared__ unsigned short Bs[2][128 * 32];
  const int tid = threadIdx.x;
  const int wave = tid >> 6, lane = tid & 63;
  const int wr = wave >> 2, wc = wave & 3;       // 32-row band / 32-col band
  const int fm = lane & 15, quad = lane >> 4;
  const int id = blockIdx.x + gridDim.x * blockIdx.y;
  const int row0 = (id & 127) << 6;
  const int col0 = (id >> 7) << 7;
  const int sArow = (tid & 255) >> 2;            // 0..63 (duplicated halves)
  const int sBrow = tid >> 2;                    // 0..127
  const int sgr = (tid & 3) * 8;

  auto issue = [&](int kt, int buf) {
    const int kk = kt * 32;
    __builtin_amdgcn_global_load_lds(
        (const __attribute__((address_space(1))) uint32_t*)
            (A + (size_t)(row0 + sArow) * 1024 + kk + sgr),
        (__attribute__((address_space(3))) uint32_t*)(&As[buf][sArow * 32 + sgr]),
        16, 0, 0);
    __builtin_amdgcn_global_load_lds(
        (const __attribute__((address_space(1))) uint32_t*)
            (Bt + (size_t)(col0 + sBrow) * 1024 + kk + sgr),
        (__attribute__((address_space(3))) uint32_t*)(&Bs[buf][sBrow * 32 + sgr]),
        16, 0, 0);
  };

  floatx4 acc[2][2];
#pragma unroll
  for (int tm = 0; tm < 2; tm++)
#pragma unroll
    for (int tn = 0; tn < 2; tn++) acc[tm][tn] = (floatx4){0.f, 0.f, 0.f, 0.f};

  const int nk = 32;  // K = 1024
  issue(0, 0);
  for (int k = 0; k < nk; k++) {
    const int cur = k & 1;
    if (k + 1 < nk) {
      issue(k + 1, cur ^ 1);
      asm volatile("s_waitcnt vmcnt(2)\ns_barrier" ::: "memory");
    } else {
      asm volatile("s_waitcnt vmcnt(0)\ns_barrier" ::: "memory");
    }
    bf16x8 a[2], b[2];
#pragma unroll
    for (int tm = 0; tm < 2; tm++)
      a[tm] = *(const bf16x8*)(&As[cur][(wr * 32 + tm * 16 + fm) * 32 + quad * 8]);
#pragma unroll
    for (int tn = 0; tn < 2; tn++)
      b[tn] = *(const bf16x8*)(&Bs[cur][(wc * 32 + tn * 16 + fm) * 32 + quad * 8]);
#pragma unroll
    for (int tm = 0; tm < 2; tm++)
#pragma unroll
      for (int tn = 0; tn < 2; tn++)
        acc[tm][tn] = __builtin_amdgcn_mfma_f32_16x16x32_bf16(a[tm], b[tn],
                                                              acc[tm][tn], 0, 0, 0);
    asm volatile("s_barrier" ::: "memory");
  }

  float aa = a_amp[0], bb = b_amp[0], pc = ph[0];
  float a2 = aa * aa, b2 = bb * bb, s = a2 + b2;
  float p0 = a2 / s, p1 = b2 / s;
  float sp0 = sqrtf(p0), sp1 = sqrtf(p1);
  float qi = 2.0f * sqrtf(p0 * p1) * pc * coh;
  float nscale = sigma + 0.1f * fabsf(qi);

#pragma unroll
  for (int tn = 0; tn < 2; tn++) {
    int col = col0 + wc * 32 + tn * 16 + fm;
    float bv = bias[col];
#pragma unroll
    for (int tm = 0; tm < 2; tm++) {
      int rbase = row0 + wr * 32 + tm * 16 + quad * 4;
#pragma unroll
      for (int r = 0; r < 4; r++) {
        int row = rbase + r;
        size_t i = (size_t)row * 512 + col;
        float itf = acc[tm][tn][r] + bv;
        float den = sp0 * bf2f(d0[i]) + sp1 * bf2f(d1[i]) + qi * itf;
        float xn = (x[i] - c1 * den) / sqa;
        if (add_noise) xn += nscale * tf_normal(k0, k1, (uint32_t)i);
        x[i] = xn;
        xbf[i] = f2bf(xn);
      }
    }
  }
}

__global__ void init_normal_kernel(float* __restrict__ x,
                                   unsigned short* __restrict__ xbf,
                                   uint32_t k0, uint32_t k1, int n) {
  int i = blockIdx.x * blockDim.x + threadIdx.x;
  if (i >= n) return;
  float v = tf_normal(k0, k1, (uint32_t)i);
  x[i] = v;
  xbf[i] = f2bf(v);
}

__global__ void final_kernel(const float* __restrict__ x,
                             const float* __restrict__ real,
                             float* __restrict__ out,
                             const float* __restrict__ a_amp,
                             const float* __restrict__ b_amp,
                             uint32_t k0, uint32_t k1, int n) {
  int i = blockIdx.x * blockDim.x + threadIdx.x;
  if (i >= n) return;
  float aa = a_amp[0], bb = b_amp[0];
  float a2 = aa * aa, b2 = bb * bb;
  float p0 = a2 / (a2 + b2);
  uint32_t o0, o1;
  tf2x32(k0, k1, 0u, 0u, o0, o1);
  uint32_t bits = o0 ^ o1;
  float u = __uint_as_float(0x3F800000u | (bits >> 9)) - 1.0f;
  float xv = x[i];
  out[i] = (u < p0) ? (0.7f * xv + 0.3f * real[i]) : xv;
}

extern "C" void kernel_launch(void* const* d_in, const int* in_sizes, int n_in,
                              void* d_out, int out_size, void* d_ws,
                              size_t ws_size, hipStream_t stream) {
  const float* real = (const float*)d_in[0];
  const float* Wq  = (const float*)d_in[2];
  const float* bq  = (const float*)d_in[3];
  const float* W01 = (const float*)d_in[4];
  const float* b01 = (const float*)d_in[5];
  const float* W02 = (const float*)d_in[6];
  const float* b02 = (const float*)d_in[7];
  const float* W11 = (const float*)d_in[8];
  const float* b11 = (const float*)d_in[9];
  const float* W12 = (const float*)d_in[10];
  const float* b12 = (const float*)d_in[11];
  const float* Wi1 = (const float*)d_in[12];
  const float* bi1 = (const float*)d_in[13];
  const float* Wi2 = (const float*)d_in[14];
  const float* bi2 = (const float*)d_in[15];
  const float* a_amp = (const float*)d_in[16];
  const float* b_amp = (const float*)d_in[17];
  const float* ph    = (const float*)d_in[18];

  const int Nn = 8192, F = 512, H = 1024;
  const int nElem = Nn * F;  // 4,194,304
  const int NSPLIT_OFF = 1 << 30;

  // workspace layout
  char* ws = (char*)d_ws;
  float* x = (float*)ws;                                   ws += (size_t)nElem * 4;
  unsigned short* xbf = (unsigned short*)ws;               ws += (size_t)nElem * 2;
  unsigned short* qf  = (unsigned short*)ws;               ws += (size_t)Nn * H * 2;
  unsigned short* h0  = (unsigned short*)ws;               ws += (size_t)Nn * H * 2;
  unsigned short* h1  = (unsigned short*)ws;               ws += (size_t)Nn * H * 2;
  unsigned short* d0  = (unsigned short*)ws;               ws += (size_t)nElem * 2;
  unsigned short* d1  = (unsigned short*)ws;               ws += (size_t)nElem * 2;
  unsigned short* Wq_t  = (unsigned short*)ws;             ws += (size_t)F * H * 2;
  unsigned short* WA_t  = (unsigned short*)ws;             ws += (size_t)(2 * H) * H * 2; // [W01_t ; W11_t]
  unsigned short* W02_t = (unsigned short*)ws;             ws += (size_t)H * F * 2;
  unsigned short* W12_t = (unsigned short*)ws;             ws += (size_t)H * F * 2;
  unsigned short* Wi1_t = (unsigned short*)ws;             ws += (size_t)(2 * F) * H * 2;
  unsigned short* Wi2_t = (unsigned short*)ws;             ws += (size_t)H * F * 2;

  dim3 tb(256);
  transpose_bf16_kernel<<<dim3(F / 32, H / 32), tb, 0, stream>>>(Wq, Wq_t, F, H);
  transpose_bf16_kernel<<<dim3(H / 32, H / 32), tb, 0, stream>>>(W01, WA_t, H, H);
  transpose_bf16_kernel<<<dim3(H / 32, H / 32), tb, 0, stream>>>(W11, WA_t + (size_t)H * H, H, H);
  transpose_bf16_kernel<<<dim3(H / 32, F / 32), tb, 0, stream>>>(W02, W02_t, H, F);
  transpose_bf16_kernel<<<dim3(H / 32, F / 32), tb, 0, stream>>>(W12, W12_t, H, F);
  transpose_bf16_kernel<<<dim3(2 * F / 32, H / 32), tb, 0, stream>>>(Wi1, Wi1_t, 2 * F, H);
  transpose_bf16_kernel<<<dim3(H / 32, F / 32), tb, 0, stream>>>(Wi2, Wi2_t, H, F);

  uint32_t kx0, kx1; tf2x32(0u, 1u, 0u, 10000u, kx0, kx1);
  init_normal_kernel<<<(nElem + 255) / 256, 256, 0, stream>>>(x, xbf, kx0, kx1, nElem);

  float sched[100];
  for (int i = 0; i < 100; i++)
    sched[i] = (float)(1e-4 + (0.02 - 1e-4) * (double)i / 99.0);
  const float decay = expf(-0.1f);
  float coh = 1.0f;

  dim3 blk(512);
  dim3 g1(H / 128 * 32);           // 256 blocks (256x128 tiles)
  dim3 g2(2 * H / 128 * 32);       // 512 blocks
  dim3 g45(F / 128 * 32, 1, 2);    // 128 x2 = 256 blocks
  dim3 g6(H / 128 * 32);           // 256 blocks
  dim3 g7(F / 128, Nn / 64);       // (4,128) = 512 blocks, 64x128 tiles

  for (int j = 0; j < 50; j++) {
    int t = 49 - j;
    // G1: qf = relu(x @ Wq + bq)
    mfma_gemm<1><<<g1, blk, 0, stream>>>(xbf, xbf, F, F, F, F, Wq_t,
                                         bq, nullptr, NSPLIT_OFF, qf, nullptr, H);
    // G2 merged: h0 = relu(qf@W01+b01), h1 = tanh(qf@W11+b11), N=2048 GEMM
    mfma_gemm<4><<<g2, blk, 0, stream>>>(qf, qf, H, H, H, H, WA_t,
                                         b01, b11, H, h0, h1, H);
    // G4/G5 z-batched: d0 = h0@W02+b02 ; d1 = h1@W12+b12
    mfma_gemm_pair<<<g45, blk, 0, stream>>>(h0, h1, W02_t, W12_t, b02, b12,
                                            d0, d1, H, F);
    // G6: qf(reused) = gelu([d0|d1] @ Wi1 + bi1)
    mfma_gemm<3><<<g6, blk, 0, stream>>>(d0, d1, F, F, F, 2 * F, Wi1_t,
                                         bi1, nullptr, NSPLIT_OFF, qf, nullptr, H);

    float schedt = sched[t];
    float alphaf = fmaxf(1.0f - schedt, 1e-8f);
    float one_m_alpha = 1.0f - alphaf;
    float sqrt_1ma = sqrtf(fmaxf(one_m_alpha, 1e-8f));
    float c1 = one_m_alpha / sqrt_1ma;
    float sqa = sqrtf(alphaf);
    float sigma = 0.0f;
    if (t > 0) {
      float ap = 1.0f - sched[t - 1];
      sigma = sqrtf(fmaxf((1.0f - ap) / one_m_alpha * (1.0f - alphaf / ap), 0.0f));
    }
    uint32_t kt0, kt1; tf2x32(0u, 1u, 0u, (uint32_t)t, kt0, kt1);
    // G7 fused: itf = qf @ Wi2 + bi2  +  DDPM update of x/xbf
    mfma_gemm_update<<<g7, blk, 0, stream>>>(
        qf, Wi2_t, bi2, d0, d1, x, xbf, a_amp, b_amp, ph, coh, c1, sqa, sigma,
        (t > 0) ? 1 : 0, kt0, kt1);
    coh *= decay;
  }

  uint32_t ku0, ku1; tf2x32(0u, 1u, 0u, 99999u, ku0, ku1);
  final_kernel<<<(nElem + 255) / 256, 256, 0, stream>>>(
      x, real, (float*)d_out, a_amp, b_amp, ku0, ku1, nElem);
}